// Round 9
// baseline (165.120 us; speedup 1.0000x reference)
//
#include <hip/hip_runtime.h>
#include <hip/hip_bf16.h>
#include <hip/hip_cooperative_groups.h>

#define N_NODES 50000
#define N_EDGES 800000
#define DIM 96
#define NPART 256                 // partitions (= blocks = CUs), 196 nodes each
#define PSZ 196
#define BINCAP 48                 // LDS bin slots per (block, partition); mean 12.2
#define BPP (NPART * BINCAP)      // 12288 global slots per partition
#define CAP 4096                  // per-partition records (mean 3125, +17 sigma)
#define EPB (N_EDGES / NPART)     // 3125 edges binned per block

namespace cg = cooperative_groups;

typedef unsigned int uint;
typedef unsigned short u16;

__device__ __forceinline__ u16 f2bf(float f) {
    __hip_bfloat16 h = __float2bfloat16(f);
    return *reinterpret_cast<u16*>(&h);
}
__device__ __forceinline__ float bf2f(u16 u) {
    return __uint_as_float(((uint)u) << 16);
}
// exact floor(t/196) for t < 65536
__device__ __forceinline__ int pdiv(int t) { return (int)(((uint)t * 85599u) >> 24); }

// ---------------------------------------------------------------------------
// Single cooperative kernel. 256 blocks x 1024 threads, 1 block/CU.
// Phase 1: Bb staging (disjoint LDS, overlapped) + x->bf16 pack + edge bin.
// grid.sync()
// Phase 2: counts scan -> compact recs -> node hist/sort -> 24-lane-group
//          gather (the latency-bound core) -> mean into A-tile -> MFMA.
// LDS layout (150272 B total, phase-1 bins alias phase-2 Axm):
//   [0      ..  83200) Axm  208*200 u16      | bins 256*48 uint (49152)
//   [83200  .. 121600) Bb   96*200 short     |   + bcnt 256 int @49152
//   [121600 .. 137984) recs 4096 uint
//   [137984 .. 146176) ssrc 4096 u16
//   [146176 .. 150272) bc/csc/hist/cur 4x256 int
// ---------------------------------------------------------------------------
__global__ __launch_bounds__(1024) void sage_all_k(
    const float* __restrict__ x, const int* __restrict__ ei,
    const float* __restrict__ Wself, const float* __restrict__ bself,
    const float* __restrict__ Wneigh, const float* __restrict__ bneigh,
    u16* __restrict__ xbf, uint* __restrict__ part_edges,
    int* __restrict__ counts, float* __restrict__ out)
{
    using short8 = __attribute__((ext_vector_type(8))) short;
    using f32x4  = __attribute__((ext_vector_type(4))) float;

    __shared__ __align__(16) char smem[150272];
    u16*   Axm  = (u16*)smem;
    short* Bb   = (short*)(smem + 83200);
    uint*  recs = (uint*)(smem + 121600);
    u16*   ssrc = (u16*)(smem + 137984);
    int*   bc   = (int*)(smem + 146176);
    int*   csc  = (int*)(smem + 147200);
    int*   hist = (int*)(smem + 148224);
    int*   cur  = (int*)(smem + 149248);
    uint*  bins = (uint*)smem;              // phase 1 (49152 B)
    int*   bcnt = (int*)(smem + 49152);     // phase 1 (1024 B)

    const int tid = threadIdx.x;
    const int b = blockIdx.x;

    // ======================= PHASE 1 =======================
    // Bb staging — LDS region disjoint from bins; overlaps everything.
    for (int idx = tid; idx < 96 * 96; idx += 1024) {
        int j = idx / 96;
        int k = idx - j * 96;
        Bb[j * 200 + k]      = (short)f2bf(Wself[idx]);
        Bb[j * 200 + 96 + k] = (short)f2bf(Wneigh[idx]);
    }

    // pack x -> xbf (grid-strided float4)
    for (int i = b * 1024 + tid; i < N_NODES * DIM / 4; i += NPART * 1024) {
        float4 v = reinterpret_cast<const float4*>(x)[i];
        ushort4 o;
        o.x = f2bf(v.x); o.y = f2bf(v.y); o.z = f2bf(v.z); o.w = f2bf(v.w);
        reinterpret_cast<ushort4*>(xbf)[i] = o;
    }

    // bin this block's 3125 edges
    if (tid < NPART) bcnt[tid] = 0;
    __syncthreads();
    for (int i = tid; i < EPB; i += 1024) {
        int e = b * EPB + i;
        int sv = ei[e];
        int tv = ei[N_EDGES + e];
        int p = pdiv(tv);
        int local = tv - p * PSZ;
        int slot = atomicAdd(&bcnt[p], 1);
        if (slot < BINCAP)
            bins[p * BINCAP + slot] = ((uint)local << 16) | (uint)sv;
    }
    __syncthreads();
    if (tid < NPART) counts[tid * NPART + b] = min(bcnt[tid], BINCAP);
    for (int i = tid; i < NPART * BINCAP; i += 1024) {
        int p = i / BINCAP;
        int s = i - p * BINCAP;
        if (s < bcnt[p])
            part_edges[(size_t)p * BPP + b * BINCAP + s] = bins[i];
    }

    cg::this_grid().sync();

    // ======================= PHASE 2 =======================
    const int p = b;
    const int node0 = p * PSZ;

    // counts row (coalesced) + scan-array init
    if (tid < 256) {
        int v = counts[p * NPART + tid];
        bc[tid] = v;
        csc[tid] = v;
        cur[tid] = 0;
    }

    // stage x-half of Axm (bins LDS is dead now; Axm aliases it)
    for (int i = tid; i < PSZ * 12; i += 1024) {
        int n = i / 12, t = i - n * 12;
        int node = node0 + n;
        short8 v = (short8)0;
        if (node < N_NODES)
            v = *reinterpret_cast<const short8*>(xbf + (size_t)node * DIM + t * 8);
        *reinterpret_cast<short8*>(&Axm[n * 200 + t * 8]) = v;
    }
    __syncthreads();

    // inclusive scan csc over 256
    for (int o = 1; o < 256; o <<= 1) {
        int v = 0;
        if (tid < 256 && tid >= o) v = csc[tid - o];
        __syncthreads();
        if (tid < 256) csc[tid] += v;
        __syncthreads();
    }
    int m = csc[255]; if (m > CAP) m = CAP;

    // compact cells -> recs
    for (int i = tid; i < NPART * BINCAP; i += 1024) {
        int cb = i / BINCAP;
        int s = i - cb * BINCAP;
        if (s < bc[cb]) {
            int dst = csc[cb] - bc[cb] + s;
            if (dst < CAP)
                recs[dst] = part_edges[(size_t)p * BPP + i];
        }
    }
    __syncthreads();

    // node histogram + scan
    for (int i = tid; i < m; i += 1024)
        atomicAdd(&cur[recs[i] >> 16], 1);
    __syncthreads();
    if (tid < 256) hist[tid] = cur[tid];
    __syncthreads();
    for (int o = 1; o < 256; o <<= 1) {
        int v = 0;
        if (tid < 256 && tid >= o) v = hist[tid - o];
        __syncthreads();
        if (tid < 256) hist[tid] += v;
        __syncthreads();
    }
    if (tid < 256) cur[tid] = hist[tid] - cur[tid];   // exclusive cursor
    __syncthreads();

    // scatter to node-sorted ssrc
    for (int i = tid; i < m; i += 1024) {
        uint r = recs[i];
        int pos = atomicAdd(&cur[r >> 16], 1);
        ssrc[pos] = (u16)(r & 0xFFFF);
    }
    __syncthreads();

    // gather + mean -> Axm[.. + 96]
    if (tid < 1008) {
        const int g = tid / 24;
        const int l = tid - g * 24;
        const int l4 = l * 4;
        for (int r = g; r < PSZ; r += 42) {
            int end = hist[r];
            int beg = (r > 0) ? hist[r - 1] : 0;
            float ax = 0.f, ay = 0.f, az = 0.f, aw = 0.f;
            int i = beg;
            for (; i + 3 < end; i += 4) {
                int s0 = ssrc[i], s1 = ssrc[i + 1], s2 = ssrc[i + 2], s3 = ssrc[i + 3];
                ushort4 v0 = *reinterpret_cast<const ushort4*>(xbf + (size_t)s0 * DIM + l4);
                ushort4 v1 = *reinterpret_cast<const ushort4*>(xbf + (size_t)s1 * DIM + l4);
                ushort4 v2 = *reinterpret_cast<const ushort4*>(xbf + (size_t)s2 * DIM + l4);
                ushort4 v3 = *reinterpret_cast<const ushort4*>(xbf + (size_t)s3 * DIM + l4);
                ax += bf2f(v0.x) + bf2f(v1.x) + bf2f(v2.x) + bf2f(v3.x);
                ay += bf2f(v0.y) + bf2f(v1.y) + bf2f(v2.y) + bf2f(v3.y);
                az += bf2f(v0.z) + bf2f(v1.z) + bf2f(v2.z) + bf2f(v3.z);
                aw += bf2f(v0.w) + bf2f(v1.w) + bf2f(v2.w) + bf2f(v3.w);
            }
            for (; i < end; i++) {
                int s = ssrc[i];
                ushort4 v = *reinterpret_cast<const ushort4*>(xbf + (size_t)s * DIM + l4);
                ax += bf2f(v.x); ay += bf2f(v.y); az += bf2f(v.z); aw += bf2f(v.w);
            }
            float inv = (end > beg) ? 1.0f / (float)(end - beg) : 0.f;
            ushort4 o;
            o.x = f2bf(ax * inv); o.y = f2bf(ay * inv);
            o.z = f2bf(az * inv); o.w = f2bf(aw * inv);
            *reinterpret_cast<ushort4*>(&Axm[r * 200 + 96 + l4]) = o;
        }
    }
    __syncthreads();

    // MFMA: 13 row-tiles of 16 rows over waves 0..12
    const int wave = tid >> 6;
    const int lane = tid & 63;
    const int quad = lane >> 4;
    const int m16  = lane & 15;

    if (wave < 13) {
        const int rloc = wave * 16;
        f32x4 acc[6];
#pragma unroll
        for (int nt = 0; nt < 6; nt++) acc[nt] = (f32x4){0.f, 0.f, 0.f, 0.f};

#pragma unroll
        for (int kt = 0; kt < 6; kt++) {
            short8 a = *reinterpret_cast<const short8*>(
                &Axm[(rloc + m16) * 200 + kt * 32 + quad * 8]);
#pragma unroll
            for (int nt = 0; nt < 6; nt++) {
                short8 bb = *reinterpret_cast<const short8*>(
                    &Bb[(nt * 16 + m16) * 200 + kt * 32 + quad * 8]);
                acc[nt] = __builtin_amdgcn_mfma_f32_16x16x32_bf16(a, bb, acc[nt], 0, 0, 0);
            }
        }

#pragma unroll
        for (int nt = 0; nt < 6; nt++) {
            int col = nt * 16 + m16;
            float bias = bself[col] + bneigh[col];
#pragma unroll
            for (int reg = 0; reg < 4; reg++) {
                int rl = rloc + quad * 4 + reg;
                int row = node0 + rl;
                if (rl < PSZ && row < N_NODES)
                    out[(size_t)row * DIM + col] = acc[nt][reg] + bias;
            }
        }
    }
}

extern "C" void kernel_launch(void* const* d_in, const int* in_sizes, int n_in,
                              void* d_out, int out_size, void* d_ws, size_t ws_size,
                              hipStream_t stream) {
    const float* x      = (const float*)d_in[0];
    const int*   ei     = (const int*)d_in[1];
    const float* Wself  = (const float*)d_in[2];
    const float* bself  = (const float*)d_in[3];
    const float* Wneigh = (const float*)d_in[4];
    const float* bneigh = (const float*)d_in[5];
    float* out = (float*)d_out;

    // Workspace (fully written before read; no memset):
    uint* part_edges = (uint*)d_ws;                               // 256*12288*4 = 12.6 MB
    int*  counts     = (int*)(part_edges + (size_t)NPART * BPP);  // 256*256*4 = 256 KB
    u16*  xbf        = (u16*)(counts + NPART * NPART);            // 9.6 MB

    void* args[] = {
        (void*)&x, (void*)&ei, (void*)&Wself, (void*)&bself,
        (void*)&Wneigh, (void*)&bneigh,
        (void*)&xbf, (void*)&part_edges, (void*)&counts, (void*)&out
    };
    hipLaunchCooperativeKernel((void*)sage_all_k, dim3(NPART), dim3(1024),
                               args, 0, stream);
}

// Round 11
// 123.470 us; speedup vs baseline: 1.3373x; 1.3373x over previous
//
#include <hip/hip_runtime.h>
#include <hip/hip_bf16.h>

#define N_NODES 50000
#define N_EDGES 800000
#define DIM 96
#define NPART 256                 // partitions of 196 target nodes
#define PSZ 196                   // nodes per partition
#define NBINBLK 196               // edge-binning blocks (4096 edges each)
#define BINCAP 48                 // slots per (partition, bin-block) cell; mean 16, +8 sigma
#define BPP (NBINBLK * BINCAP)    // 9408 slots per partition
#define CAP 4096                  // recs/ssrc buffer (mean 3125, sigma 56 -> +17 sigma)
#define NPACK_BLOCKS 4688         // ceil(4.8M elems / (256*4))

typedef unsigned int uint;
typedef unsigned short u16;
using u16x8 = __attribute__((ext_vector_type(8))) unsigned short;

__device__ __forceinline__ u16 f2bf(float f) {
    __hip_bfloat16 h = __float2bfloat16(f);
    return *reinterpret_cast<u16*>(&h);
}
__device__ __forceinline__ float bf2f(u16 u) {
    return __uint_as_float(((uint)u) << 16);
}
// exact floor(t/196) for t < 50000 (overestimate < 0.003 << 1/196 slack)
__device__ __forceinline__ int pdiv(int t) { return (int)(((uint)t * 85599u) >> 24); }

// ---------------------------------------------------------------------------
// K1: blocks [0,196): bin 4096 contiguous edges into fixed per-(p,b) cells.
//     blocks [196,...): pack x f32 -> bf16.
// NOTE: 196*4096 = 802816 > N_EDGES — the tail guard is load-bearing
// (round-10 dropped it and binned 2816 phantom edges -> absmax 0.40).
// ---------------------------------------------------------------------------
__global__ __launch_bounds__(256) void packbin_k(
    const float* __restrict__ x, const int* __restrict__ ei,
    u16* __restrict__ xbf, uint* __restrict__ part_edges,
    int* __restrict__ counts)
{
    __shared__ uint bins[NPART * BINCAP];   // 49152 B
    __shared__ int  bcnt[NPART];
    const int tid = threadIdx.x;

    if (blockIdx.x >= NBINBLK) {
        int pb = blockIdx.x - NBINBLK;
        int i4 = (pb * 256 + tid) * 4;
        if (i4 < N_NODES * DIM) {
            float4 v = *reinterpret_cast<const float4*>(x + i4);
            ushort4 o;
            o.x = f2bf(v.x); o.y = f2bf(v.y); o.z = f2bf(v.z); o.w = f2bf(v.w);
            *reinterpret_cast<ushort4*>(xbf + i4) = o;
        }
        return;
    }

    for (int i = tid; i < NPART; i += 256) bcnt[i] = 0;
    __syncthreads();

    const int e0 = blockIdx.x * 4096 + tid * 16;
    if (e0 + 16 <= N_EDGES) {
#pragma unroll
        for (int j = 0; j < 4; j++) {
            int4 s = *reinterpret_cast<const int4*>(ei + e0 + j * 4);
            int4 t = *reinterpret_cast<const int4*>(ei + N_EDGES + e0 + j * 4);
            int ss[4] = {s.x, s.y, s.z, s.w};
            int tt[4] = {t.x, t.y, t.z, t.w};
#pragma unroll
            for (int k = 0; k < 4; k++) {
                int p = pdiv(tt[k]);
                int local = tt[k] - p * PSZ;
                int slot = atomicAdd(&bcnt[p], 1);
                if (slot < BINCAP)
                    bins[p * BINCAP + slot] = ((uint)local << 16) | (uint)ss[k];
            }
        }
    } else {
        for (int j = 0; j < 16; j++) {
            int e = e0 + j;
            if (e < N_EDGES) {
                int sv = ei[e];
                int tv = ei[N_EDGES + e];
                int p = pdiv(tv);
                int local = tv - p * PSZ;
                int slot = atomicAdd(&bcnt[p], 1);
                if (slot < BINCAP)
                    bins[p * BINCAP + slot] = ((uint)local << 16) | (uint)sv;
            }
        }
    }
    __syncthreads();

    for (int p = tid; p < NPART; p += 256)
        counts[p * NBINBLK + blockIdx.x] = min(bcnt[p], BINCAP);

    for (int i = tid; i < NPART * BINCAP; i += 256) {
        int p = i / BINCAP;
        int s = i - p * BINCAP;
        if (s < bcnt[p])
            part_edges[(size_t)p * BPP + blockIdx.x * BINCAP + s] = bins[i];
    }
}

// ---------------------------------------------------------------------------
// One-wave inclusive scan of a 256-int LDS array (wave 0 only; caller must
// __syncthreads() before and after). 4 elems/lane + shfl_up wave scan.
// ---------------------------------------------------------------------------
__device__ __forceinline__ void wave_scan256(int* a, int tid) {
    if (tid < 64) {
        int v0 = a[tid * 4], v1 = a[tid * 4 + 1], v2 = a[tid * 4 + 2], v3 = a[tid * 4 + 3];
        int s01 = v0 + v1;
        int s = s01 + v2 + v3;              // chunk sum
        int inc = s;
#pragma unroll
        for (int off = 1; off < 64; off <<= 1) {
            int n = __shfl_up(inc, off, 64);
            if (tid >= off) inc += n;
        }
        int base = inc - s;                  // exclusive prefix of chunk
        a[tid * 4]     = base + v0;
        a[tid * 4 + 1] = base + s01;
        a[tid * 4 + 2] = base + s01 + v2;
        a[tid * 4 + 3] = base + s;           // = inc
    }
}

// ---------------------------------------------------------------------------
// K2: one block per partition (196 nodes), 1024 threads, 256 blocks.
// counts scan -> compact recs -> node hist/sort -> 12-lane x 16B gather
// (85 groups, unroll x4 => ~340 rows in flight/CU) -> mean -> MFMA.
// ---------------------------------------------------------------------------
__global__ __launch_bounds__(1024) void fused_k(
    const u16* __restrict__ xbf,
    const uint* __restrict__ part_edges,
    const int* __restrict__ counts,
    const float* __restrict__ Wself, const float* __restrict__ bself,
    const float* __restrict__ Wneigh, const float* __restrict__ bneigh,
    float* __restrict__ out)
{
    using short8 = __attribute__((ext_vector_type(8))) short;
    using f32x4  = __attribute__((ext_vector_type(4))) float;

    __shared__ u16   Axm[208 * 200];     // 83200 B
    __shared__ short Bb[96 * 200];       // 38400 B
    __shared__ uint  recs[CAP];          // 16384 B
    __shared__ u16   ssrc[CAP];          //  8192 B
    __shared__ int   bc[256];
    __shared__ int   csc[256];
    __shared__ int   hist[256];
    __shared__ int   cur[256];

    const int tid = threadIdx.x;
    const int p = blockIdx.x;
    const int node0 = p * PSZ;

    // ---- Bb from global (independent; overlaps sort setup) ----
    for (int idx = tid; idx < 96 * 96; idx += 1024) {
        int j = idx / 96;
        int k = idx - j * 96;
        Bb[j * 200 + k]      = (short)f2bf(Wself[idx]);
        Bb[j * 200 + 96 + k] = (short)f2bf(Wneigh[idx]);
    }

    // ---- counts row (coalesced) + init ----
    if (tid < 256) {
        int v = (tid < NBINBLK) ? counts[p * NBINBLK + tid] : 0;
        bc[tid] = v;
        csc[tid] = v;
        cur[tid] = 0;
    }

    // ---- stage x-half of Axm ----
    for (int i = tid; i < PSZ * 12; i += 1024) {
        int n = i / 12, t = i - n * 12;
        int node = node0 + n;
        short8 v = (short8)0;
        if (node < N_NODES)
            v = *reinterpret_cast<const short8*>(xbf + (size_t)node * DIM + t * 8);
        *reinterpret_cast<short8*>(&Axm[n * 200 + t * 8]) = v;
    }
    __syncthreads();

    wave_scan256(csc, tid);
    __syncthreads();
    int m = csc[255]; if (m > CAP) m = CAP;

    // ---- compact cells -> recs ----
    for (int i = tid; i < NBINBLK * BINCAP; i += 1024) {
        int b = i / BINCAP;
        int s = i - b * BINCAP;
        if (s < bc[b]) {
            int dst = csc[b] - bc[b] + s;
            if (dst < CAP)
                recs[dst] = part_edges[(size_t)p * BPP + i];
        }
    }
    __syncthreads();

    // ---- node histogram + scan ----
    for (int i = tid; i < m; i += 1024)
        atomicAdd(&cur[recs[i] >> 16], 1);
    __syncthreads();
    if (tid < 256) hist[tid] = cur[tid];
    __syncthreads();
    wave_scan256(hist, tid);
    __syncthreads();
    if (tid < 256) cur[tid] = hist[tid] - cur[tid];   // exclusive cursor
    __syncthreads();

    // ---- scatter to node-sorted ssrc ----
    for (int i = tid; i < m; i += 1024) {
        uint r = recs[i];
        int pos = atomicAdd(&cur[r >> 16], 1);
        ssrc[pos] = (u16)(r & 0xFFFF);
    }
    __syncthreads();

    // ---- gather + mean -> Axm[.. + 96]: 85 groups of 12 lanes, 16B/lane ----
    if (tid < 1020) {
        const int g = tid / 12;
        const int l = tid - g * 12;
        const int l8 = l * 8;                 // u16 offset in row
        for (int r = g; r < PSZ; r += 85) {
            int end = hist[r];
            int beg = (r > 0) ? hist[r - 1] : 0;
            float a0 = 0.f, a1 = 0.f, a2 = 0.f, a3 = 0.f;
            float a4 = 0.f, a5 = 0.f, a6 = 0.f, a7 = 0.f;
            int i = beg;
            for (; i + 3 < end; i += 4) {
                int s0 = ssrc[i], s1 = ssrc[i + 1], s2 = ssrc[i + 2], s3 = ssrc[i + 3];
                u16x8 v0 = *reinterpret_cast<const u16x8*>(xbf + (size_t)s0 * DIM + l8);
                u16x8 v1 = *reinterpret_cast<const u16x8*>(xbf + (size_t)s1 * DIM + l8);
                u16x8 v2 = *reinterpret_cast<const u16x8*>(xbf + (size_t)s2 * DIM + l8);
                u16x8 v3 = *reinterpret_cast<const u16x8*>(xbf + (size_t)s3 * DIM + l8);
                a0 += bf2f(v0[0]) + bf2f(v1[0]) + bf2f(v2[0]) + bf2f(v3[0]);
                a1 += bf2f(v0[1]) + bf2f(v1[1]) + bf2f(v2[1]) + bf2f(v3[1]);
                a2 += bf2f(v0[2]) + bf2f(v1[2]) + bf2f(v2[2]) + bf2f(v3[2]);
                a3 += bf2f(v0[3]) + bf2f(v1[3]) + bf2f(v2[3]) + bf2f(v3[3]);
                a4 += bf2f(v0[4]) + bf2f(v1[4]) + bf2f(v2[4]) + bf2f(v3[4]);
                a5 += bf2f(v0[5]) + bf2f(v1[5]) + bf2f(v2[5]) + bf2f(v3[5]);
                a6 += bf2f(v0[6]) + bf2f(v1[6]) + bf2f(v2[6]) + bf2f(v3[6]);
                a7 += bf2f(v0[7]) + bf2f(v1[7]) + bf2f(v2[7]) + bf2f(v3[7]);
            }
            for (; i < end; i++) {
                int s = ssrc[i];
                u16x8 v = *reinterpret_cast<const u16x8*>(xbf + (size_t)s * DIM + l8);
                a0 += bf2f(v[0]); a1 += bf2f(v[1]); a2 += bf2f(v[2]); a3 += bf2f(v[3]);
                a4 += bf2f(v[4]); a5 += bf2f(v[5]); a6 += bf2f(v[6]); a7 += bf2f(v[7]);
            }
            float inv = (end > beg) ? 1.0f / (float)(end - beg) : 0.f;
            u16x8 o;
            o[0] = f2bf(a0 * inv); o[1] = f2bf(a1 * inv);
            o[2] = f2bf(a2 * inv); o[3] = f2bf(a3 * inv);
            o[4] = f2bf(a4 * inv); o[5] = f2bf(a5 * inv);
            o[6] = f2bf(a6 * inv); o[7] = f2bf(a7 * inv);
            *reinterpret_cast<u16x8*>(&Axm[r * 200 + 96 + l8]) = o;
        }
    }
    __syncthreads();

    // ---- MFMA: 13 row-tiles of 16 over waves 0..12 ----
    const int wave = tid >> 6;
    const int lane = tid & 63;
    const int quad = lane >> 4;
    const int m16  = lane & 15;

    if (wave < 13) {
        const int rloc = wave * 16;
        f32x4 acc[6];
#pragma unroll
        for (int nt = 0; nt < 6; nt++) acc[nt] = (f32x4){0.f, 0.f, 0.f, 0.f};

#pragma unroll
        for (int kt = 0; kt < 6; kt++) {
            short8 a = *reinterpret_cast<const short8*>(
                &Axm[(rloc + m16) * 200 + kt * 32 + quad * 8]);
#pragma unroll
            for (int nt = 0; nt < 6; nt++) {
                short8 b = *reinterpret_cast<const short8*>(
                    &Bb[(nt * 16 + m16) * 200 + kt * 32 + quad * 8]);
                acc[nt] = __builtin_amdgcn_mfma_f32_16x16x32_bf16(a, b, acc[nt], 0, 0, 0);
            }
        }

#pragma unroll
        for (int nt = 0; nt < 6; nt++) {
            int col = nt * 16 + m16;
            float bias = bself[col] + bneigh[col];
#pragma unroll
            for (int reg = 0; reg < 4; reg++) {
                int rl = rloc + quad * 4 + reg;
                int row = node0 + rl;
                if (rl < PSZ && row < N_NODES)
                    out[(size_t)row * DIM + col] = acc[nt][reg] + bias;
            }
        }
    }
}

extern "C" void kernel_launch(void* const* d_in, const int* in_sizes, int n_in,
                              void* d_out, int out_size, void* d_ws, size_t ws_size,
                              hipStream_t stream) {
    const float* x      = (const float*)d_in[0];
    const int*   ei     = (const int*)d_in[1];
    const float* Wself  = (const float*)d_in[2];
    const float* bself  = (const float*)d_in[3];
    const float* Wneigh = (const float*)d_in[4];
    const float* bneigh = (const float*)d_in[5];
    float* out = (float*)d_out;

    // Workspace (fully written before read; no memset):
    uint* part_edges = (uint*)d_ws;                                 // 256*9408*4 = 9.63 MB
    int*  counts     = (int*)(part_edges + (size_t)NPART * BPP);    // 256*196*4 = 200 KB
    u16*  xbf        = (u16*)(counts + NPART * NBINBLK);            // 9.6 MB

    packbin_k<<<NBINBLK + NPACK_BLOCKS, 256, 0, stream>>>(
        x, ei, xbf, part_edges, counts);
    fused_k<<<NPART, 1024, 0, stream>>>(
        xbf, part_edges, counts, Wself, bself, Wneigh, bneigh, out);
}